// Round 12
// baseline (91.899 us; speedup 1.0000x reference)
//
#include <hip/hip_runtime.h>

// ---------------------------------------------------------------------------
// Patcher: 8 images (1024x1024x3 f32), 8 boxes each (64x64), per box:
//   crop -> bilinear up 128 -> conv3x3 SAME + tanh -> loss += mean((im-pb)^2)
//   -> bilinear down 64 -> scatter -> (clip is a no-op for these inputs)
// Output: patched images (25165824 f32) ++ cumsum of per-image losses (8 f32).
//
// Round 12: shrink the graph. r11 (67.5us) = fused(~60: 57us mixed-stream
// copy wall + patch hidden under it) + init kernel + finalize kernel + node
// gaps (~7.5us structure). The copy wall is empirical (5 implementations
// incl. AMD's blit at ~57us; pure-read ~8 TB/s, pure-write 7 TB/s, mixed
// 3.5 TB/s turnaround). Remaining lever = dispatch structure:
//  - finalize folded into fused: last patch block (patchDone counter, 512
//    release atomics total) does the fixed-order loss cumsum
//  - init kernel replaced by one 512B hipMemsetAsync node
// Graph: memset + ONE kernel. Fused copy/patch paths unchanged from r11.
// ---------------------------------------------------------------------------

#define PTHR 256
#define NPB 512    // 64 boxes x 8 bands
#define NCOPY 2048 // copy blocks; 2048 x 3072 chunks = whole image block
#define NBLK (NPB + NCOPY)

#define IMG_FLOATS (1024 * 1024 * 3)        // 3145728
#define LOSS_OFF ((size_t)IMG_FLOATS * 8)   // 25165824

typedef float f32x4 __attribute__((ext_vector_type(4)));

__device__ __forceinline__ int iclamp(int v, int lo, int hi) {
  return v < lo ? lo : (v > hi ? hi : v);
}
__device__ __forceinline__ float tanh_fast(float x) {
  float t = __expf(2.0f * x);
  return 1.0f - 2.0f / (t + 1.0f);  // inf-safe tanh
}

// ---------------- fused kernel: patch bands + box-skipping copy -------------
// ws layout (ints): [0..63] boxDone counters, [64] patchDone, zeroed by the
// 512B memset node each call. wsLoss: 512 floats at byte 512.
__global__ __launch_bounds__(PTHR, 2) void fused_kernel(
    const float* __restrict__ gin, const float* __restrict__ gW,
    const int* __restrict__ gbox, float* __restrict__ gout,
    int* __restrict__ wsI, float* __restrict__ wsLoss) {
  __shared__ float sCrop[12][193];   // 9264 B (patch path only)
  __shared__ float sPlane[18][129];  // 9288 B
  __shared__ float sWred[4];

  const int bid = blockIdx.x;
  const int tid = threadIdx.x;

  if (bid >= NPB) {
    // =================== copy path: 4 image rows per block ===============
    const int cid = bid - NPB;        // 0..2047
    const int img = cid >> 8;         // 256 blocks per image
    const int row0 = (cid & 255) * 4; // first of 4 rows
    const size_t fbase = (size_t)cid * 12288;  // first float of block

    int by[8], bs[8];
#pragma unroll
    for (int j = 0; j < 8; ++j) {
      by[j] = gbox[img * 16 + 2 * j];
      bs[j] = gbox[img * 16 + 2 * j + 1] * 3;  // box x-span start, floats
    }
    // any box rows intersect my 4 rows?
    bool anyRow = false;
#pragma unroll
    for (int j = 0; j < 8; ++j)
      anyRow = anyRow || ((by[j] < row0 + 4) && (row0 < by[j] + 64));

    const f32x4* src = (const f32x4*)(gin + fbase);
    f32x4* dst = (f32x4*)(gout + fbase);
    f32x4 v[12];
#pragma unroll
    for (int q = 0; q < 12; ++q) v[q] = src[tid + q * PTHR];

    if (!anyRow) {  // fast path: nothing to skip
#pragma unroll
      for (int q = 0; q < 12; ++q)
        __builtin_nontemporal_store(v[q], &dst[tid + q * PTHR]);
    } else {
#pragma unroll
      for (int q = 0; q < 12; ++q) {
        const int c = tid + q * PTHR;  // chunk in block, 0..3071
        const int r = c / 768;         // row within my 4
        const int xf = (c - r * 768) * 4;  // first float within row
        const int y = row0 + r;
        bool anyOv = false, fullIn = false;
#pragma unroll
        for (int j = 0; j < 8; ++j) {
          const bool rowHit = (unsigned)(y - by[j]) < 64u;
          anyOv = anyOv || (rowHit && (xf + 4 > bs[j]) && (xf < bs[j] + 192));
          fullIn = fullIn || (rowHit && (xf >= bs[j]) && (xf + 4 <= bs[j] + 192));
        }
        if (!anyOv) {
          __builtin_nontemporal_store(v[q], &dst[tid + q * PTHR]);
        } else if (!fullIn) {
          // straddles a box edge: per-float (rare)
#pragma unroll
          for (int i = 0; i < 4; ++i) {
            const int xfi = xf + i;
            bool inside = false;
#pragma unroll
            for (int j = 0; j < 8; ++j)
              inside = inside || (((unsigned)(y - by[j]) < 64u) &&
                                  (xfi >= bs[j]) && (xfi < bs[j] + 192));
            if (!inside) gout[fbase + (size_t)c * 4 + i] = v[q][i];
          }
        }
        // fullIn: patch blocks own these pixels entirely
      }
    }
    return;
  }

  // ====================== patch path (r5/r11, unchanged) ==================
  const int box = bid >> 3;   // 0..63
  const int band = bid & 7;   // 0..7
  const int img = box >> 3;
  const int k = box & 7;
  int* boxDone = wsI;         // [64] per-box completed-band counters
  int* patchDone = wsI + 64;  // fused-finalize counter

  int jy[8], jx[8];
#pragma unroll
  for (int j = 0; j < 8; ++j) {
    jy[j] = gbox[img * 16 + 2 * j];
    jx[j] = gbox[img * 16 + 2 * j + 1];
  }
  int y0 = 0, x0 = 0;
#pragma unroll
  for (int j = 0; j < 8; ++j)
    if (j == k) { y0 = jy[j]; x0 = jx[j]; }

  bool ov[8];
  bool hasPred = false, hasSucc = false;
#pragma unroll
  for (int j = 0; j < 8; ++j) {
    int dy = y0 - jy[j]; dy = dy < 0 ? -dy : dy;
    int dx = x0 - jx[j]; dx = dx < 0 ? -dx : dx;
    ov[j] = (dy < 64) && (dx < 64);
    hasPred = hasPred || (j < k && ov[j]);
    hasSucc = hasSucc || (j > k && ov[j]);
  }

  // ---- wait for overlapping predecessor boxes (all 8 bands done; RARE) ----
  if (tid == 0 && hasPred) {
#pragma unroll
    for (int j = 0; j < 8; ++j) {
      if (j < k && ov[j]) {
        while (__hip_atomic_load(&boxDone[img * 8 + j], __ATOMIC_RELAXED,
                                 __HIP_MEMORY_SCOPE_AGENT) < 8) {
          __builtin_amdgcn_s_sleep(2);
        }
      }
    }
    __builtin_amdgcn_fence(__ATOMIC_ACQUIRE, "agent");
  }
  __syncthreads();

  const size_t ibase = (size_t)img * IMG_FLOATS;
  const int cropBase = 8 * band - 2;  // global crop row of sCrop[0]

  // ---- stage 1: crop rows -> LDS (12 rows x 64 px x 3ch = 768 px) ----
#pragma unroll
  for (int q = 0; q < 3; ++q) {
    const int idx = tid + q * PTHR;
    const int r = idx >> 6, col = idx & 63;
    const int gr = iclamp(cropBase + r, 0, 63);
    const int gy = y0 + gr, gx = x0 + col;
    const float* src = gin;
    if (hasPred) {
      bool covered = false;
#pragma unroll
      for (int j = 0; j < 8; ++j) {
        bool cj = (j < k) && ((unsigned)(gy - jy[j]) < 64u) &&
                  ((unsigned)(gx - jx[j]) < 64u);
        covered = covered || cj;
      }
      if (covered) src = gout;
    }
    const size_t a = ibase + ((size_t)gy * 1024 + gx) * 3;
    sCrop[r][col * 3 + 0] = src[a + 0];
    sCrop[r][col * 3 + 1] = src[a + 1];
    sCrop[r][col * 3 + 2] = src[a + 2];
  }
  __syncthreads();

  // thread geometry: own tile = 4 plane rows x 2 cols
  const int m = tid >> 6, tx = tid & 63;
  const int r0 = 16 * band + 4 * m;  // global plane row base of my tile
  const int hg = (tid < 128) ? 16 * band - 1 : 16 * band + 16;
  const int hh = iclamp(hg, 0, 127);
  const int hx = tid & 127;
  const int hslot = (tid < 128) ? 0 : 17;

  float lossAcc = 0.f;

#pragma unroll 1
  for (int c = 0; c < 3; ++c) {
    float wk[27];
#pragma unroll
    for (int t9 = 0; t9 < 9; ++t9)
#pragma unroll
      for (int ci = 0; ci < 3; ++ci) wk[ci * 9 + t9] = gW[(t9 * 3 + ci) * 3 + c];

    float acc[4][2];
#pragma unroll
    for (int p = 0; p < 4; ++p) { acc[p][0] = 0.f; acc[p][1] = 0.f; }
    float pbown[4][2];

#pragma unroll
    for (int ci = 0; ci < 3; ++ci) {
      float cv[4][3];
#pragma unroll
      for (int a = 0; a < 4; ++a)
#pragma unroll
        for (int b = 0; b < 3; ++b)
          cv[a][b] = sCrop[2 * m + 1 + a][iclamp(tx - 1 + b, 0, 63) * 3 + ci];
      float tmp[4][4];
#pragma unroll
      for (int a = 0; a < 4; ++a) {
        tmp[a][0] = 0.75f * cv[a][0] + 0.25f * cv[a][1];
        tmp[a][1] = 0.25f * cv[a][0] + 0.75f * cv[a][1];
        tmp[a][2] = 0.75f * cv[a][1] + 0.25f * cv[a][2];
        tmp[a][3] = 0.25f * cv[a][1] + 0.75f * cv[a][2];
      }
#pragma unroll
      for (int i = 0; i < 6; ++i) {
        float pr[4];
        const int a = i >> 1;
        const float w = (i & 1) ? 0.25f : 0.75f;
#pragma unroll
        for (int j = 0; j < 4; ++j)
          pr[j] = w * tmp[a][j] + (1.0f - w) * tmp[a + 1][j];
        if (i == 0 && r0 == 0) { pr[0] = pr[1] = pr[2] = pr[3] = 0.f; }
        if (i == 5 && r0 == 124) { pr[0] = pr[1] = pr[2] = pr[3] = 0.f; }
        if (tx == 0) pr[0] = 0.f;
        if (tx == 63) pr[3] = 0.f;
        if (ci == c && i >= 1 && i <= 4) {
          pbown[i - 1][0] = pr[1];
          pbown[i - 1][1] = pr[2];
        }
#pragma unroll
        for (int p = 0; p < 4; ++p) {
          const int du = i - p;
          if (du >= 0 && du < 3) {
#pragma unroll
            for (int dv = 0; dv < 3; ++dv) {
              const float wt = wk[ci * 9 + du * 3 + dv];
              acc[p][0] += wt * pr[dv];
              acc[p][1] += wt * pr[1 + dv];
            }
          }
        }
      }
    }
#pragma unroll
    for (int p = 0; p < 4; ++p)
#pragma unroll
      for (int q = 0; q < 2; ++q) {
        const float imv = tanh_fast(acc[p][q]);
        const float d = imv - pbown[p][q];
        lossAcc += d * d;
        sPlane[4 * m + p + 1][2 * tx + q] = imv;
      }

    // halo plane px (recomputed; local rows 0 and 17)
    float hacc = 0.f;
#pragma unroll
    for (int ci = 0; ci < 3; ++ci) {
#pragma unroll
      for (int du = 0; du < 3; ++du) {
        const int U = hh - 1 + du;
        if (U >= 0 && U < 128) {
          const int Lr = (U - 1) >> 1;
          const float wr = (U & 1) ? 0.75f : 0.25f;
          const int l0 = Lr - cropBase, l1 = l0 + 1;
#pragma unroll
          for (int dv = 0; dv < 3; ++dv) {
            const int V = hx - 1 + dv;
            if (V >= 0 && V < 128) {
              const int Lc = (V - 1) >> 1;
              const float wc = (V & 1) ? 0.75f : 0.25f;
              const int c0 = iclamp(Lc, 0, 63) * 3 + ci;
              const int c1 = iclamp(Lc + 1, 0, 63) * 3 + ci;
              const float v0 = wc * sCrop[l0][c0] + (1.0f - wc) * sCrop[l0][c1];
              const float v1 = wc * sCrop[l1][c0] + (1.0f - wc) * sCrop[l1][c1];
              hacc += wk[ci * 9 + du * 3 + dv] * (wr * v0 + (1.0f - wr) * v1);
            }
          }
        }
      }
    }
    sPlane[hslot][hx] = tanh_fast(hacc);
    __syncthreads();

    // downsample 128->64 (4-tap antialiased) for my 8 output rows
    constexpr float W37 = 0.75f / 1.75f;
    constexpr float W17 = 0.25f / 1.75f;
    const int pbase = 16 * band - 1;
#pragma unroll
    for (int q2 = 0; q2 < 2; ++q2) {
      const int idx = tid + q2 * PTHR;
      const int Y = 8 * band + (idx >> 6), X = idx & 63;
      float wy[4] = {0.125f, 0.375f, 0.375f, 0.125f};
      float wx[4] = {0.125f, 0.375f, 0.375f, 0.125f};
      if (Y == 0) { wy[0] = 0.f; wy[1] = W37; wy[2] = W37; wy[3] = W17; }
      if (Y == 63) { wy[0] = W17; wy[1] = W37; wy[2] = W37; wy[3] = 0.f; }
      if (X == 0) { wx[0] = 0.f; wx[1] = W37; wx[2] = W37; wx[3] = W17; }
      if (X == 63) { wx[0] = W17; wx[1] = W37; wx[2] = W37; wx[3] = 0.f; }
      float sum = 0.f;
#pragma unroll
      for (int t2 = 0; t2 < 4; ++t2) {
        const int ryl = iclamp(2 * Y - 1 + t2, 0, 127) - pbase;
        float rs = 0.f;
#pragma unroll
        for (int u = 0; u < 4; ++u)
          rs += wx[u] * sPlane[ryl][iclamp(2 * X - 1 + u, 0, 127)];
        sum += wy[t2] * rs;
      }
      gout[ibase + ((size_t)(y0 + Y) * 1024 + (x0 + X)) * 3 + c] = sum;
    }
    __syncthreads();  // before sPlane reuse by next channel
  }

  // ---- band loss partial: block reduce (4 waves) -> ws[bid] ----
#pragma unroll
  for (int mm = 32; mm >= 1; mm >>= 1) lossAcc += __shfl_xor(lossAcc, mm, 64);
  if ((tid & 63) == 0) sWred[tid >> 6] = lossAcc;
  __syncthreads();

  if (tid == 0) {
    wsLoss[bid] = sWred[0] + sWred[1] + sWred[2] + sWred[3];  // raw band sum

    // publish to overlapping successor boxes (RARE) -- wsLoss store above is
    // also covered by the fence below.
    __threadfence();
    if (hasSucc) {
      __hip_atomic_fetch_add(&boxDone[img * 8 + k], 1, __ATOMIC_RELEASE,
                             __HIP_MEMORY_SCOPE_AGENT);
    }

    // ---- fused finalize: last patch block does the fixed-order cumsum ----
    const int prev = __hip_atomic_fetch_add(patchDone, 1, __ATOMIC_ACQ_REL,
                                            __HIP_MEMORY_SCOPE_AGENT);
    if (prev == NPB - 1) {
      float run = 0.f;
      for (int im = 0; im < 8; ++im) {
        float s = 0.f;
        for (int i = 0; i < 64; ++i) s += wsLoss[im * 64 + i];  // fixed order
        run += s / 49152.0f;  // mean over 128*128*3
        gout[LOSS_OFF + im] = run;
      }
    }
  }
}

extern "C" void kernel_launch(void* const* d_in, const int* in_sizes, int n_in,
                              void* d_out, int out_size, void* d_ws, size_t ws_size,
                              hipStream_t stream) {
  (void)in_sizes; (void)n_in; (void)out_size; (void)ws_size;
  const float* gin = (const float*)d_in[0];   // images (8,1024,1024,3) f32
  const float* gW = (const float*)d_in[1];    // W (3,3,3,3) f32, HWIO
  const int* gbox = (const int*)d_in[2];      // box_yx (8,8,2) i32
  float* gout = (float*)d_out;
  int* wsI = (int*)d_ws;                      // boxDone[64], patchDone at [64]
  float* wsLoss = (float*)d_ws + 128;         // 512 floats at byte 512

  (void)hipMemsetAsync(d_ws, 0, 512, stream);  // zero counters (replay-safe)
  hipLaunchKernelGGL(fused_kernel, dim3(NBLK), dim3(PTHR), 0, stream,
                     gin, gW, gbox, gout, wsI, wsLoss);
}

// Round 13
// 68.283 us; speedup vs baseline: 1.3459x; 1.3459x over previous
//
#include <hip/hip_runtime.h>

// ---------------------------------------------------------------------------
// Patcher: 8 images (1024x1024x3 f32), 8 boxes each (64x64), per box:
//   crop -> bilinear up 128 -> conv3x3 SAME + tanh -> loss += mean((im-pb)^2)
//   -> bilinear down 64 -> scatter -> (clip is a no-op for these inputs)
// Output: patched images (25165824 f32) ++ cumsum of per-image losses (8 f32).
//
// Round 13: REVERT r12's in-kernel finalize (regression 67.5 -> 91.9us).
// r12 moved a threadfence + device-scope ACQ_REL atomic into the hot path of
// all 512 patch blocks, concurrent with the copy stream -> the r1 cache-
// maintenance-storm failure mode re-introduced (+20us in-kernel). Back to the
// r11 structure (best: 67.5us):
//   memset(512B)  -> zero flag/counter words  [replaces r11's init kernel,
//                                              the only surviving r12 trim]
//   fused_kernel  -> blocks 0..511 patch bands (fences ONLY on rare overlap
//                    paths), blocks 512..2559 box-skipping copy; patch hides
//                    under the ~57us mixed-stream copy wall
//   finalize      -> 1-block fixed-order loss cumsum
// Copy wall is empirical: 5 implementations incl. AMD's blit all ~57us.
// ---------------------------------------------------------------------------

#define PTHR 256
#define NPB 512    // 64 boxes x 8 bands
#define NCOPY 2048 // copy blocks; 2048 x 3072 chunks = whole image block
#define NBLK (NPB + NCOPY)

#define IMG_FLOATS (1024 * 1024 * 3)        // 3145728
#define LOSS_OFF ((size_t)IMG_FLOATS * 8)   // 25165824

typedef float f32x4 __attribute__((ext_vector_type(4)));

__device__ __forceinline__ int iclamp(int v, int lo, int hi) {
  return v < lo ? lo : (v > hi ? hi : v);
}
__device__ __forceinline__ float tanh_fast(float x) {
  float t = __expf(2.0f * x);
  return 1.0f - 2.0f / (t + 1.0f);  // inf-safe tanh
}

// ---------------- fused kernel: patch bands + box-skipping copy -------------
__global__ __launch_bounds__(PTHR, 2) void fused_kernel(
    const float* __restrict__ gin, const float* __restrict__ gW,
    const int* __restrict__ gbox, float* __restrict__ gout,
    int* __restrict__ wsI, float* __restrict__ wsLoss) {
  __shared__ float sCrop[12][193];   // 9264 B (patch path only)
  __shared__ float sPlane[18][129];  // 9288 B
  __shared__ float sWred[4];

  const int bid = blockIdx.x;
  const int tid = threadIdx.x;

  if (bid >= NPB) {
    // =================== copy path: 4 image rows per block ===============
    const int cid = bid - NPB;        // 0..2047
    const int img = cid >> 8;         // 256 blocks per image
    const int row0 = (cid & 255) * 4; // first of 4 rows
    const size_t fbase = (size_t)cid * 12288;  // first float of block

    int by[8], bs[8];
#pragma unroll
    for (int j = 0; j < 8; ++j) {
      by[j] = gbox[img * 16 + 2 * j];
      bs[j] = gbox[img * 16 + 2 * j + 1] * 3;  // box x-span start, floats
    }
    // any box rows intersect my 4 rows?
    bool anyRow = false;
#pragma unroll
    for (int j = 0; j < 8; ++j)
      anyRow = anyRow || ((by[j] < row0 + 4) && (row0 < by[j] + 64));

    const f32x4* src = (const f32x4*)(gin + fbase);
    f32x4* dst = (f32x4*)(gout + fbase);
    f32x4 v[12];
#pragma unroll
    for (int q = 0; q < 12; ++q) v[q] = src[tid + q * PTHR];

    if (!anyRow) {  // fast path: nothing to skip
#pragma unroll
      for (int q = 0; q < 12; ++q)
        __builtin_nontemporal_store(v[q], &dst[tid + q * PTHR]);
    } else {
#pragma unroll
      for (int q = 0; q < 12; ++q) {
        const int c = tid + q * PTHR;  // chunk in block, 0..3071
        const int r = c / 768;         // row within my 4
        const int xf = (c - r * 768) * 4;  // first float within row
        const int y = row0 + r;
        bool anyOv = false, fullIn = false;
#pragma unroll
        for (int j = 0; j < 8; ++j) {
          const bool rowHit = (unsigned)(y - by[j]) < 64u;
          anyOv = anyOv || (rowHit && (xf + 4 > bs[j]) && (xf < bs[j] + 192));
          fullIn = fullIn || (rowHit && (xf >= bs[j]) && (xf + 4 <= bs[j] + 192));
        }
        if (!anyOv) {
          __builtin_nontemporal_store(v[q], &dst[tid + q * PTHR]);
        } else if (!fullIn) {
          // straddles a box edge: per-float (rare)
#pragma unroll
          for (int i = 0; i < 4; ++i) {
            const int xfi = xf + i;
            bool inside = false;
#pragma unroll
            for (int j = 0; j < 8; ++j)
              inside = inside || (((unsigned)(y - by[j]) < 64u) &&
                                  (xfi >= bs[j]) && (xfi < bs[j] + 192));
            if (!inside) gout[fbase + (size_t)c * 4 + i] = v[q][i];
          }
        }
        // fullIn: patch blocks own these pixels entirely
      }
    }
    return;
  }

  // ====================== patch path (r5/r11, unchanged) ==================
  const int box = bid >> 3;   // 0..63
  const int band = bid & 7;   // 0..7
  const int img = box >> 3;
  const int k = box & 7;
  int* boxDone = wsI;  // [64] per-box completed-band counters

  int jy[8], jx[8];
#pragma unroll
  for (int j = 0; j < 8; ++j) {
    jy[j] = gbox[img * 16 + 2 * j];
    jx[j] = gbox[img * 16 + 2 * j + 1];
  }
  int y0 = 0, x0 = 0;
#pragma unroll
  for (int j = 0; j < 8; ++j)
    if (j == k) { y0 = jy[j]; x0 = jx[j]; }

  bool ov[8];
  bool hasPred = false, hasSucc = false;
#pragma unroll
  for (int j = 0; j < 8; ++j) {
    int dy = y0 - jy[j]; dy = dy < 0 ? -dy : dy;
    int dx = x0 - jx[j]; dx = dx < 0 ? -dx : dx;
    ov[j] = (dy < 64) && (dx < 64);
    hasPred = hasPred || (j < k && ov[j]);
    hasSucc = hasSucc || (j > k && ov[j]);
  }

  // ---- wait for overlapping predecessor boxes (all 8 bands done; RARE) ----
  if (tid == 0 && hasPred) {
#pragma unroll
    for (int j = 0; j < 8; ++j) {
      if (j < k && ov[j]) {
        while (__hip_atomic_load(&boxDone[img * 8 + j], __ATOMIC_RELAXED,
                                 __HIP_MEMORY_SCOPE_AGENT) < 8) {
          __builtin_amdgcn_s_sleep(2);
        }
      }
    }
    __builtin_amdgcn_fence(__ATOMIC_ACQUIRE, "agent");
  }
  __syncthreads();

  const size_t ibase = (size_t)img * IMG_FLOATS;
  const int cropBase = 8 * band - 2;  // global crop row of sCrop[0]

  // ---- stage 1: crop rows -> LDS (12 rows x 64 px x 3ch = 768 px) ----
#pragma unroll
  for (int q = 0; q < 3; ++q) {
    const int idx = tid + q * PTHR;
    const int r = idx >> 6, col = idx & 63;
    const int gr = iclamp(cropBase + r, 0, 63);
    const int gy = y0 + gr, gx = x0 + col;
    const float* src = gin;
    if (hasPred) {
      bool covered = false;
#pragma unroll
      for (int j = 0; j < 8; ++j) {
        bool cj = (j < k) && ((unsigned)(gy - jy[j]) < 64u) &&
                  ((unsigned)(gx - jx[j]) < 64u);
        covered = covered || cj;
      }
      if (covered) src = gout;
    }
    const size_t a = ibase + ((size_t)gy * 1024 + gx) * 3;
    sCrop[r][col * 3 + 0] = src[a + 0];
    sCrop[r][col * 3 + 1] = src[a + 1];
    sCrop[r][col * 3 + 2] = src[a + 2];
  }
  __syncthreads();

  // thread geometry: own tile = 4 plane rows x 2 cols
  const int m = tid >> 6, tx = tid & 63;
  const int r0 = 16 * band + 4 * m;  // global plane row base of my tile
  const int hg = (tid < 128) ? 16 * band - 1 : 16 * band + 16;
  const int hh = iclamp(hg, 0, 127);
  const int hx = tid & 127;
  const int hslot = (tid < 128) ? 0 : 17;

  float lossAcc = 0.f;

#pragma unroll 1
  for (int c = 0; c < 3; ++c) {
    float wk[27];
#pragma unroll
    for (int t9 = 0; t9 < 9; ++t9)
#pragma unroll
      for (int ci = 0; ci < 3; ++ci) wk[ci * 9 + t9] = gW[(t9 * 3 + ci) * 3 + c];

    float acc[4][2];
#pragma unroll
    for (int p = 0; p < 4; ++p) { acc[p][0] = 0.f; acc[p][1] = 0.f; }
    float pbown[4][2];

#pragma unroll
    for (int ci = 0; ci < 3; ++ci) {
      float cv[4][3];
#pragma unroll
      for (int a = 0; a < 4; ++a)
#pragma unroll
        for (int b = 0; b < 3; ++b)
          cv[a][b] = sCrop[2 * m + 1 + a][iclamp(tx - 1 + b, 0, 63) * 3 + ci];
      float tmp[4][4];
#pragma unroll
      for (int a = 0; a < 4; ++a) {
        tmp[a][0] = 0.75f * cv[a][0] + 0.25f * cv[a][1];
        tmp[a][1] = 0.25f * cv[a][0] + 0.75f * cv[a][1];
        tmp[a][2] = 0.75f * cv[a][1] + 0.25f * cv[a][2];
        tmp[a][3] = 0.25f * cv[a][1] + 0.75f * cv[a][2];
      }
#pragma unroll
      for (int i = 0; i < 6; ++i) {
        float pr[4];
        const int a = i >> 1;
        const float w = (i & 1) ? 0.25f : 0.75f;
#pragma unroll
        for (int j = 0; j < 4; ++j)
          pr[j] = w * tmp[a][j] + (1.0f - w) * tmp[a + 1][j];
        if (i == 0 && r0 == 0) { pr[0] = pr[1] = pr[2] = pr[3] = 0.f; }
        if (i == 5 && r0 == 124) { pr[0] = pr[1] = pr[2] = pr[3] = 0.f; }
        if (tx == 0) pr[0] = 0.f;
        if (tx == 63) pr[3] = 0.f;
        if (ci == c && i >= 1 && i <= 4) {
          pbown[i - 1][0] = pr[1];
          pbown[i - 1][1] = pr[2];
        }
#pragma unroll
        for (int p = 0; p < 4; ++p) {
          const int du = i - p;
          if (du >= 0 && du < 3) {
#pragma unroll
            for (int dv = 0; dv < 3; ++dv) {
              const float wt = wk[ci * 9 + du * 3 + dv];
              acc[p][0] += wt * pr[dv];
              acc[p][1] += wt * pr[1 + dv];
            }
          }
        }
      }
    }
#pragma unroll
    for (int p = 0; p < 4; ++p)
#pragma unroll
      for (int q = 0; q < 2; ++q) {
        const float imv = tanh_fast(acc[p][q]);
        const float d = imv - pbown[p][q];
        lossAcc += d * d;
        sPlane[4 * m + p + 1][2 * tx + q] = imv;
      }

    // halo plane px (recomputed; local rows 0 and 17)
    float hacc = 0.f;
#pragma unroll
    for (int ci = 0; ci < 3; ++ci) {
#pragma unroll
      for (int du = 0; du < 3; ++du) {
        const int U = hh - 1 + du;
        if (U >= 0 && U < 128) {
          const int Lr = (U - 1) >> 1;
          const float wr = (U & 1) ? 0.75f : 0.25f;
          const int l0 = Lr - cropBase, l1 = l0 + 1;
#pragma unroll
          for (int dv = 0; dv < 3; ++dv) {
            const int V = hx - 1 + dv;
            if (V >= 0 && V < 128) {
              const int Lc = (V - 1) >> 1;
              const float wc = (V & 1) ? 0.75f : 0.25f;
              const int c0 = iclamp(Lc, 0, 63) * 3 + ci;
              const int c1 = iclamp(Lc + 1, 0, 63) * 3 + ci;
              const float v0 = wc * sCrop[l0][c0] + (1.0f - wc) * sCrop[l0][c1];
              const float v1 = wc * sCrop[l1][c0] + (1.0f - wc) * sCrop[l1][c1];
              hacc += wk[ci * 9 + du * 3 + dv] * (wr * v0 + (1.0f - wr) * v1);
            }
          }
        }
      }
    }
    sPlane[hslot][hx] = tanh_fast(hacc);
    __syncthreads();

    // downsample 128->64 (4-tap antialiased) for my 8 output rows
    constexpr float W37 = 0.75f / 1.75f;
    constexpr float W17 = 0.25f / 1.75f;
    const int pbase = 16 * band - 1;
#pragma unroll
    for (int q2 = 0; q2 < 2; ++q2) {
      const int idx = tid + q2 * PTHR;
      const int Y = 8 * band + (idx >> 6), X = idx & 63;
      float wy[4] = {0.125f, 0.375f, 0.375f, 0.125f};
      float wx[4] = {0.125f, 0.375f, 0.375f, 0.125f};
      if (Y == 0) { wy[0] = 0.f; wy[1] = W37; wy[2] = W37; wy[3] = W17; }
      if (Y == 63) { wy[0] = W17; wy[1] = W37; wy[2] = W37; wy[3] = 0.f; }
      if (X == 0) { wx[0] = 0.f; wx[1] = W37; wx[2] = W37; wx[3] = W17; }
      if (X == 63) { wx[0] = W17; wx[1] = W37; wx[2] = W37; wx[3] = 0.f; }
      float sum = 0.f;
#pragma unroll
      for (int t2 = 0; t2 < 4; ++t2) {
        const int ryl = iclamp(2 * Y - 1 + t2, 0, 127) - pbase;
        float rs = 0.f;
#pragma unroll
        for (int u = 0; u < 4; ++u)
          rs += wx[u] * sPlane[ryl][iclamp(2 * X - 1 + u, 0, 127)];
        sum += wy[t2] * rs;
      }
      gout[ibase + ((size_t)(y0 + Y) * 1024 + (x0 + X)) * 3 + c] = sum;
    }
    __syncthreads();  // before sPlane reuse by next channel
  }

  // ---- band loss partial: block reduce (4 waves) -> ws[bid] ----
#pragma unroll
  for (int mm = 32; mm >= 1; mm >>= 1) lossAcc += __shfl_xor(lossAcc, mm, 64);
  if ((tid & 63) == 0) sWred[tid >> 6] = lossAcc;
  __syncthreads();
  if (tid == 0)
    wsLoss[bid] = sWred[0] + sWred[1] + sWred[2] + sWred[3];  // raw sum

  // ---- publish to overlapping successor boxes only (RARE) ----
  if (hasSucc) {
    __syncthreads();
    if (tid == 0) {
      __threadfence();
      __hip_atomic_fetch_add(&boxDone[img * 8 + k], 1, __ATOMIC_RELEASE,
                             __HIP_MEMORY_SCOPE_AGENT);
    }
  }
}

// ------------------------- kernel 3: loss cumsum ---------------------------
__global__ __launch_bounds__(64) void finalize_kernel(
    const float* __restrict__ wsLoss, float* __restrict__ gout) {
  __shared__ float simg[8];
  const int t = threadIdx.x;
  if (t < 8) {
    float s = 0.f;
    for (int i = 0; i < 64; ++i) s += wsLoss[t * 64 + i];  // fixed order
    simg[t] = s / 49152.0f;  // mean over 128*128*3, summed per image
  }
  __syncthreads();
  if (t == 0) {
    float run = 0.f;
#pragma unroll
    for (int im = 0; im < 8; ++im) {
      run += simg[im];
      gout[LOSS_OFF + im] = run;
    }
  }
}

extern "C" void kernel_launch(void* const* d_in, const int* in_sizes, int n_in,
                              void* d_out, int out_size, void* d_ws, size_t ws_size,
                              hipStream_t stream) {
  (void)in_sizes; (void)n_in; (void)out_size; (void)ws_size;
  const float* gin = (const float*)d_in[0];   // images (8,1024,1024,3) f32
  const float* gW = (const float*)d_in[1];    // W (3,3,3,3) f32, HWIO
  const int* gbox = (const int*)d_in[2];      // box_yx (8,8,2) i32
  float* gout = (float*)d_out;
  int* wsI = (int*)d_ws;                      // boxDone[64] at byte 0
  float* wsLoss = (float*)d_ws + 128;         // 512 floats at byte 512

  (void)hipMemsetAsync(d_ws, 0, 512, stream);  // zero counters (replay-safe)
  hipLaunchKernelGGL(fused_kernel, dim3(NBLK), dim3(PTHR), 0, stream,
                     gin, gW, gbox, gout, wsI, wsLoss);
  hipLaunchKernelGGL(finalize_kernel, dim3(1), dim3(64), 0, stream,
                     wsLoss, gout);
}